// Round 1
// baseline (1765.909 us; speedup 1.0000x reference)
//
#include <hip/hip_runtime.h>

#define N_NODES 100000
#define N_EDGES 1000000
#define IN_CH 128
#define HID_CH 64
#define N_CLS 40

static inline int cdiv(int a, int b) { return (a + b - 1) / b; }

// ---------------- degree / norm kernels ----------------

__global__ void deg_kernel(const int* __restrict__ cols, float* __restrict__ deg, int E) {
    int i = blockIdx.x * blockDim.x + threadIdx.x;
    if (i < E) atomicAdd(&deg[cols[i]], 1.0f);
}

__global__ void dinv_kernel(float* __restrict__ deg, int n) {
    int i = blockIdx.x * blockDim.x + threadIdx.x;
    if (i < n) {
        float d = deg[i];
        deg[i] = (d > 0.f) ? rsqrtf(d) : 0.f;
    }
}

__global__ void norm_kernel(const int* __restrict__ rows, const int* __restrict__ cols,
                            const float* __restrict__ dinv, float* __restrict__ norm, int E) {
    int i = blockIdx.x * blockDim.x + threadIdx.x;
    if (i < E) norm[i] = dinv[rows[i]] * dinv[cols[i]];
}

// ---------------- tiled f32 GEMM:  Y[N][COLS] = X[N][K] @ W[K][COLS] (+B) ----------------
// 64-row tile per block, weights fully staged in LDS, x staged in 64-wide k-chunks.

template<int K, int COLS, int RPT, int CPT>
__launch_bounds__(256)
__global__ void gemm_kernel(const float* __restrict__ X,
                            const float* __restrict__ W,
                            const float* __restrict__ B,   // nullable
                            float* __restrict__ Y, int N) {
    constexpr int TILE_R = 64;
    constexpr int KC = 64;
    constexpr int NCHUNK = K / KC;
    constexpr int NCOLG = COLS / CPT;
    constexpr int NROWG = TILE_R / RPT;
    static_assert(NROWG * NCOLG == 256, "thread tiling must use 256 threads");

    __shared__ float wlds[K * COLS];
    __shared__ float xs[TILE_R][KC + 4];

    const int tid = threadIdx.x;
    const int r0 = blockIdx.x * TILE_R;

    // stage W (whole matrix) into LDS
    constexpr int W4 = K * COLS / 4;
    const float4* Wg = reinterpret_cast<const float4*>(W);
    float4* wl4 = reinterpret_cast<float4*>(wlds);
    for (int i = tid; i < W4; i += 256) wl4[i] = Wg[i];

    const int tcol = tid % NCOLG;
    const int trow = tid / NCOLG;
    const int cbase = tcol * CPT;
    const int rbase = trow * RPT;

    float acc[RPT][CPT];
#pragma unroll
    for (int i = 0; i < RPT; ++i)
#pragma unroll
        for (int j = 0; j < CPT; ++j) acc[i][j] = 0.f;

    for (int ch = 0; ch < NCHUNK; ++ch) {
        __syncthreads();   // xs reuse (and first pass: before reading wlds too)
#pragma unroll
        for (int j = 0; j < 4; ++j) {
            int flat4 = tid + 256 * j;       // 1024 float4 = 64 rows x 64 floats
            int rr = flat4 >> 4;
            int k4 = flat4 & 15;
            float4 v = make_float4(0.f, 0.f, 0.f, 0.f);
            int gr = r0 + rr;
            if (gr < N)
                v = *reinterpret_cast<const float4*>(&X[(size_t)gr * K + ch * KC + k4 * 4]);
            *reinterpret_cast<float4*>(&xs[rr][k4 * 4]) = v;
        }
        __syncthreads();
#pragma unroll
        for (int kk = 0; kk < KC; ++kk) {
            const int k = ch * KC + kk;
            float xv[RPT];
#pragma unroll
            for (int i = 0; i < RPT; ++i) xv[i] = xs[rbase + i][kk];
            float wv[CPT];
#pragma unroll
            for (int j = 0; j < CPT; ++j) wv[j] = wlds[k * COLS + cbase + j];
#pragma unroll
            for (int i = 0; i < RPT; ++i)
#pragma unroll
                for (int j = 0; j < CPT; ++j)
                    acc[i][j] = fmaf(xv[i], wv[j], acc[i][j]);
        }
    }

#pragma unroll
    for (int i = 0; i < RPT; ++i) {
        int r = r0 + rbase + i;
        if (r < N) {
#pragma unroll
            for (int j = 0; j < CPT; ++j) {
                float v = acc[i][j];
                if (B) v += B[cbase + j];
                Y[(size_t)r * COLS + cbase + j] = v;
            }
        }
    }
}

// ---------------- edge scatter:  AGG[col] += norm * H[row]  ----------------

template<int C>
__launch_bounds__(256)
__global__ void scatter_kernel(const int* __restrict__ rows,
                               const int* __restrict__ cols,
                               const float* __restrict__ norm,
                               const float* __restrict__ H,
                               float* __restrict__ AGG, int E) {
    constexpr int TPE = C / 4;   // threads per edge (float4 each)
    int gid = blockIdx.x * blockDim.x + threadIdx.x;
    int e = gid / TPE;
    int c4 = gid - e * TPE;
    if (e >= E) return;
    int r = rows[e];
    int co = cols[e];
    float nv = norm[e];
    float4 hv = *reinterpret_cast<const float4*>(&H[(size_t)r * C + c4 * 4]);
    float* dst = &AGG[(size_t)co * C + c4 * 4];
    atomicAdd(dst + 0, nv * hv.x);
    atomicAdd(dst + 1, nv * hv.y);
    atomicAdd(dst + 2, nv * hv.z);
    atomicAdd(dst + 3, nv * hv.w);
}

// ---------------- in-place relu (float4) ----------------

__global__ void relu_kernel(float* __restrict__ p, int n4) {
    int i = blockIdx.x * blockDim.x + threadIdx.x;
    if (i < n4) {
        float4 v = reinterpret_cast<float4*>(p)[i];
        v.x = fmaxf(v.x, 0.f);
        v.y = fmaxf(v.y, 0.f);
        v.z = fmaxf(v.z, 0.f);
        v.w = fmaxf(v.w, 0.f);
        reinterpret_cast<float4*>(p)[i] = v;
    }
}

// ---------------- launcher ----------------

extern "C" void kernel_launch(void* const* d_in, const int* in_sizes, int n_in,
                              void* d_out, int out_size, void* d_ws, size_t ws_size,
                              hipStream_t stream) {
    const float* x       = (const float*)d_in[0];
    const int*   eidx    = (const int*)d_in[1];
    const float* w1_init = (const float*)d_in[2];
    const float* w1_root = (const float*)d_in[3];
    const float* b1      = (const float*)d_in[4];
    const float* w2_init = (const float*)d_in[5];
    const float* w2_root = (const float*)d_in[6];
    const float* b2      = (const float*)d_in[7];
    float* out = (float*)d_out;

    const int* rows = eidx;                // edge_index[0]
    const int* cols = eidx + N_EDGES;      // edge_index[1]

    // workspace layout (floats)
    float* ws   = (float*)d_ws;
    float* norm = ws;                                   // 1,000,000
    float* dinv = ws + 1000000;                         //   100,000  (deg in-place)
    float* h0   = ws + 1100000;                         // 6,400,000 (reused as h2: 4,000,000)
    float* agg1 = ws + 7500000;                         // 6,400,000 (becomes h after relu)
    float* h2   = h0;

    const int B = 256;

    // degree -> dinv -> per-edge norm
    hipMemsetAsync(dinv, 0, N_NODES * sizeof(float), stream);
    deg_kernel<<<cdiv(N_EDGES, B), B, 0, stream>>>(cols, dinv, N_EDGES);
    dinv_kernel<<<cdiv(N_NODES, B), B, 0, stream>>>(dinv, N_NODES);
    norm_kernel<<<cdiv(N_EDGES, B), B, 0, stream>>>(rows, cols, dinv, norm, N_EDGES);

    // ---- layer 1 ----
    // h0 = x @ w1_init ; agg1 = x @ w1_root + b1
    gemm_kernel<IN_CH, HID_CH, 4, 4><<<cdiv(N_NODES, 64), B, 0, stream>>>(x, w1_init, nullptr, h0, N_NODES);
    gemm_kernel<IN_CH, HID_CH, 4, 4><<<cdiv(N_NODES, 64), B, 0, stream>>>(x, w1_root, b1, agg1, N_NODES);
    // agg1[col] += norm * h0[row]
    scatter_kernel<HID_CH><<<cdiv(N_EDGES * (HID_CH / 4), B), B, 0, stream>>>(rows, cols, norm, h0, agg1, N_EDGES);
    // h = relu(agg1) in place (double relu in ref == single relu)
    relu_kernel<<<cdiv(N_NODES * HID_CH / 4, B), B, 0, stream>>>(agg1, N_NODES * HID_CH / 4);

    // ---- layer 2 ----
    // h2 = h @ w2_init ; out = h @ w2_root + b2
    gemm_kernel<HID_CH, N_CLS, 2, 5><<<cdiv(N_NODES, 64), B, 0, stream>>>(agg1, w2_init, nullptr, h2, N_NODES);
    gemm_kernel<HID_CH, N_CLS, 2, 5><<<cdiv(N_NODES, 64), B, 0, stream>>>(agg1, w2_root, b2, out, N_NODES);
    // out[col] += norm * h2[row]
    scatter_kernel<N_CLS><<<cdiv(N_EDGES * (N_CLS / 4), B), B, 0, stream>>>(rows, cols, norm, h2, out, N_EDGES);
    relu_kernel<<<cdiv(N_NODES * N_CLS / 4, B), B, 0, stream>>>(out, N_NODES * N_CLS / 4);
}

// Round 2
// 723.926 us; speedup vs baseline: 2.4393x; 2.4393x over previous
//
#include <hip/hip_runtime.h>

#define N_NODES 100000
#define N_EDGES 1000000
#define IN_CH 128
#define HID_CH 64
#define N_CLS 40

static inline int cdiv(int a, int b) { return (a + b - 1) / b; }

// ---------------- histogram / dinv ----------------

__global__ void hist_kernel(const int* __restrict__ cols, int* __restrict__ counts, int E) {
    int i = blockIdx.x * blockDim.x + threadIdx.x;
    if (i < E) atomicAdd(&counts[cols[i]], 1);
}

__global__ void dinv_kernel(const int* __restrict__ counts, float* __restrict__ dinv, int n) {
    int i = blockIdx.x * blockDim.x + threadIdx.x;
    if (i < n) {
        int d = counts[i];
        dinv[i] = (d > 0) ? rsqrtf((float)d) : 0.f;
    }
}

// ---------------- single-block exclusive scan over counts -> offsets, cursor ----------------

__global__ __launch_bounds__(1024)
void scan_kernel(const int* __restrict__ counts, int* __restrict__ offsets,
                 int* __restrict__ cursor, int n) {
    constexpr int T = 1024;
    const int CH = (n + T - 1) / T;   // 98 for n=100000
    __shared__ int part[T];
    int t = threadIdx.x;
    int base = t * CH;
    int s = 0;
    for (int k = 0; k < CH; ++k) {
        int i = base + k;
        if (i < n) s += counts[i];
    }
    part[t] = s;
    __syncthreads();
    // Hillis-Steele inclusive scan
    for (int off = 1; off < T; off <<= 1) {
        int v = (t >= off) ? part[t - off] : 0;
        __syncthreads();
        part[t] += v;
        __syncthreads();
    }
    int run = (t > 0) ? part[t - 1] : 0;   // exclusive base for this chunk
    for (int k = 0; k < CH; ++k) {
        int i = base + k;
        if (i < n) {
            offsets[i] = run;
            cursor[i] = run;
            run += counts[i];
        }
    }
    if (t == T - 1) offsets[n] = part[T - 1];
}

// ---------------- CSR fill: srow[pos] = row for each edge, bucketed by col ----------------

__global__ void fill_kernel(const int* __restrict__ rows, const int* __restrict__ cols,
                            int* __restrict__ cursor, int* __restrict__ srow, int E) {
    int e = blockIdx.x * blockDim.x + threadIdx.x;
    if (e < E) {
        int pos = atomicAdd(&cursor[cols[e]], 1);
        srow[pos] = rows[e];
    }
}

// ---------------- tiled f32 GEMM:  Y[N][COLS] = X[N][K] @ W[K][COLS] (+B) ----------------

template<int K, int COLS, int RPT, int CPT>
__launch_bounds__(256)
__global__ void gemm_kernel(const float* __restrict__ X,
                            const float* __restrict__ W,
                            const float* __restrict__ B,   // nullable
                            float* __restrict__ Y, int N) {
    constexpr int TILE_R = 64;
    constexpr int KC = 64;
    constexpr int NCHUNK = K / KC;
    constexpr int NCOLG = COLS / CPT;
    constexpr int NROWG = TILE_R / RPT;
    static_assert(NROWG * NCOLG == 256, "thread tiling must use 256 threads");

    __shared__ float wlds[K * COLS];
    __shared__ float xs[TILE_R][KC + 4];

    const int tid = threadIdx.x;
    const int r0 = blockIdx.x * TILE_R;

    constexpr int W4 = K * COLS / 4;
    const float4* Wg = reinterpret_cast<const float4*>(W);
    float4* wl4 = reinterpret_cast<float4*>(wlds);
    for (int i = tid; i < W4; i += 256) wl4[i] = Wg[i];

    const int tcol = tid % NCOLG;
    const int trow = tid / NCOLG;
    const int cbase = tcol * CPT;
    const int rbase = trow * RPT;

    float acc[RPT][CPT];
#pragma unroll
    for (int i = 0; i < RPT; ++i)
#pragma unroll
        for (int j = 0; j < CPT; ++j) acc[i][j] = 0.f;

    for (int ch = 0; ch < NCHUNK; ++ch) {
        __syncthreads();
#pragma unroll
        for (int j = 0; j < 4; ++j) {
            int flat4 = tid + 256 * j;       // 1024 float4 = 64 rows x 64 floats
            int rr = flat4 >> 4;
            int k4 = flat4 & 15;
            float4 v = make_float4(0.f, 0.f, 0.f, 0.f);
            int gr = r0 + rr;
            if (gr < N)
                v = *reinterpret_cast<const float4*>(&X[(size_t)gr * K + ch * KC + k4 * 4]);
            *reinterpret_cast<float4*>(&xs[rr][k4 * 4]) = v;
        }
        __syncthreads();
#pragma unroll
        for (int kk = 0; kk < KC; ++kk) {
            const int k = ch * KC + kk;
            float xv[RPT];
#pragma unroll
            for (int i = 0; i < RPT; ++i) xv[i] = xs[rbase + i][kk];
            float wv[CPT];
#pragma unroll
            for (int j = 0; j < CPT; ++j) wv[j] = wlds[k * COLS + cbase + j];
#pragma unroll
            for (int i = 0; i < RPT; ++i)
#pragma unroll
                for (int j = 0; j < CPT; ++j)
                    acc[i][j] = fmaf(xv[i], wv[j], acc[i][j]);
        }
    }

#pragma unroll
    for (int i = 0; i < RPT; ++i) {
        int r = r0 + rbase + i;
        if (r < N) {
#pragma unroll
            for (int j = 0; j < CPT; ++j) {
                float v = acc[i][j];
                if (B) v += B[cbase + j];
                Y[(size_t)r * COLS + cbase + j] = v;
            }
        }
    }
}

// ---------------- pull aggregation:  Y[node] = relu(Y[node] + sum_e norm * H[srow]) ----------------
// C/4 threads per node, each owning one float4 of the channel dim. Per edge the
// TPE lanes read a contiguous C*4-byte burst of H.

template<int C>
__launch_bounds__(256)
__global__ void pull_kernel(const int* __restrict__ offsets,
                            const int* __restrict__ srow,
                            const float* __restrict__ dinv,
                            const float* __restrict__ H,
                            float* __restrict__ Y, int N) {
    constexpr int TPE = C / 4;
    int gid = blockIdx.x * blockDim.x + threadIdx.x;
    int node = gid / TPE;
    int lane = gid - node * TPE;
    if (node >= N) return;

    int e0 = offsets[node];
    int e1 = offsets[node + 1];
    float dc = dinv[node];

    const float4* H4 = reinterpret_cast<const float4*>(H);
    float4 acc = make_float4(0.f, 0.f, 0.f, 0.f);
    for (int j = e0; j < e1; ++j) {
        int r = srow[j];
        float nv = dc * dinv[r];
        float4 hv = H4[(size_t)r * TPE + lane];
        acc.x = fmaf(nv, hv.x, acc.x);
        acc.y = fmaf(nv, hv.y, acc.y);
        acc.z = fmaf(nv, hv.z, acc.z);
        acc.w = fmaf(nv, hv.w, acc.w);
    }

    float4* Y4 = reinterpret_cast<float4*>(Y);
    size_t yi = (size_t)node * TPE + lane;
    float4 y = Y4[yi];
    y.x = fmaxf(y.x + acc.x, 0.f);
    y.y = fmaxf(y.y + acc.y, 0.f);
    y.z = fmaxf(y.z + acc.z, 0.f);
    y.w = fmaxf(y.w + acc.w, 0.f);
    Y4[yi] = y;
}

// ---------------- launcher ----------------

extern "C" void kernel_launch(void* const* d_in, const int* in_sizes, int n_in,
                              void* d_out, int out_size, void* d_ws, size_t ws_size,
                              hipStream_t stream) {
    const float* x       = (const float*)d_in[0];
    const int*   eidx    = (const int*)d_in[1];
    const float* w1_init = (const float*)d_in[2];
    const float* w1_root = (const float*)d_in[3];
    const float* b1      = (const float*)d_in[4];
    const float* w2_init = (const float*)d_in[5];
    const float* w2_root = (const float*)d_in[6];
    const float* b2      = (const float*)d_in[7];
    float* out = (float*)d_out;

    const int* rows = eidx;                // edge_index[0] (source)
    const int* cols = eidx + N_EDGES;      // edge_index[1] (target)

    // workspace layout (4-byte units, all 16B-aligned)
    char* wsb = (char*)d_ws;
    float* dinv    = (float*)(wsb);                        //   100,000 f
    int*   counts  = (int*)  (wsb + 100000u * 4);          //   100,000 i
    int*   offsets = (int*)  (wsb + 200000u * 4);          //   100,001 i (pad to 100,004)
    int*   cursor  = (int*)  (wsb + 300004u * 4);          //   100,000 i
    int*   srow    = (int*)  (wsb + 400004u * 4);          // 1,000,000 i
    float* h0      = (float*)(wsb + 1400004u * 4);         // 6,400,000 f  (reused as h2)
    float* agg1    = (float*)(wsb + 7800004u * 4);         // 6,400,000 f
    float* h2      = h0;
    // total: 14,200,004 * 4 B = 56.8 MB

    const int B = 256;

    // ---- graph prep: degree, dinv, CSR by target ----
    hipMemsetAsync(counts, 0, N_NODES * sizeof(int), stream);
    hist_kernel<<<cdiv(N_EDGES, B), B, 0, stream>>>(cols, counts, N_EDGES);
    dinv_kernel<<<cdiv(N_NODES, B), B, 0, stream>>>(counts, dinv, N_NODES);
    scan_kernel<<<1, 1024, 0, stream>>>(counts, offsets, cursor, N_NODES);
    fill_kernel<<<cdiv(N_EDGES, B), B, 0, stream>>>(rows, cols, cursor, srow, N_EDGES);

    // ---- layer 1 ----
    gemm_kernel<IN_CH, HID_CH, 4, 4><<<cdiv(N_NODES, 64), B, 0, stream>>>(x, w1_init, nullptr, h0, N_NODES);
    gemm_kernel<IN_CH, HID_CH, 4, 4><<<cdiv(N_NODES, 64), B, 0, stream>>>(x, w1_root, b1, agg1, N_NODES);
    // agg1 = relu(agg1 + pull(h0))   [double relu in ref == single relu]
    pull_kernel<HID_CH><<<cdiv(N_NODES * (HID_CH / 4), B), B, 0, stream>>>(offsets, srow, dinv, h0, agg1, N_NODES);

    // ---- layer 2 ----
    gemm_kernel<HID_CH, N_CLS, 2, 5><<<cdiv(N_NODES, 64), B, 0, stream>>>(agg1, w2_init, nullptr, h2, N_NODES);
    gemm_kernel<HID_CH, N_CLS, 2, 5><<<cdiv(N_NODES, 64), B, 0, stream>>>(agg1, w2_root, b2, out, N_NODES);
    // out = relu(out + pull(h2))
    pull_kernel<N_CLS><<<cdiv(N_NODES * (N_CLS / 4), B), B, 0, stream>>>(offsets, srow, dinv, h2, out, N_NODES);
}

// Round 3
// 472.729 us; speedup vs baseline: 3.7356x; 1.5314x over previous
//
#include <hip/hip_runtime.h>

#define N_NODES 100000
#define N_EDGES 1000000
#define IN_CH 128
#define HID_CH 64
#define N_CLS 40

static inline int cdiv(int a, int b) { return (a + b - 1) / b; }

// ---------------- histogram / dinv ----------------

__global__ void hist_kernel(const int* __restrict__ cols, int* __restrict__ counts, int E) {
    int i = blockIdx.x * blockDim.x + threadIdx.x;
    if (i < E) atomicAdd(&counts[cols[i]], 1);
}

__global__ void dinv_kernel(const int* __restrict__ counts, float* __restrict__ dinv, int n) {
    int i = blockIdx.x * blockDim.x + threadIdx.x;
    if (i < n) {
        int d = counts[i];
        dinv[i] = (d > 0) ? rsqrtf((float)d) : 0.f;
    }
}

// ---------------- 3-phase device scan (counts -> offsets, cursor) ----------------
// Phase 1: per-block sums (1024 counts / block, int4 per thread)

__global__ __launch_bounds__(256)
void block_sum_kernel(const int* __restrict__ counts, int* __restrict__ bsum, int n) {
    __shared__ int red[256];
    int t = threadIdx.x;
    int i0 = blockIdx.x * 1024 + t * 4;
    int s = 0;
    if (i0 < n) {   // n % 4 == 0, so the whole int4 is in-bounds
        int4 v = *reinterpret_cast<const int4*>(&counts[i0]);
        s = v.x + v.y + v.z + v.w;
    }
    red[t] = s;
    __syncthreads();
    for (int off = 128; off > 0; off >>= 1) {
        if (t < off) red[t] += red[t + off];
        __syncthreads();
    }
    if (t == 0) bsum[blockIdx.x] = red[0];
}

// Phase 2: one small block scans the block sums (nb <= 128), exclusive in place.
// Also writes offsets[n] = total.

__global__ __launch_bounds__(128)
void scan_bsum_kernel(int* __restrict__ bsum, int* __restrict__ offsets, int nb, int n) {
    __shared__ int part[128];
    int t = threadIdx.x;
    part[t] = (t < nb) ? bsum[t] : 0;
    __syncthreads();
    for (int off = 1; off < 128; off <<= 1) {
        int v = (t >= off) ? part[t - off] : 0;
        __syncthreads();
        part[t] += v;
        __syncthreads();
    }
    if (t < nb) bsum[t] = (t > 0) ? part[t - 1] : 0;   // exclusive
    if (t == 127) offsets[n] = part[127];
}

// Phase 3: block-local exclusive scan + block base -> offsets, cursor

__global__ __launch_bounds__(256)
void final_offsets_kernel(const int* __restrict__ counts, const int* __restrict__ bsum,
                          int* __restrict__ offsets, int* __restrict__ cursor, int n) {
    __shared__ int part[256];
    int t = threadIdx.x;
    int i0 = blockIdx.x * 1024 + t * 4;
    int4 c = make_int4(0, 0, 0, 0);
    if (i0 < n) c = *reinterpret_cast<const int4*>(&counts[i0]);
    part[t] = c.x + c.y + c.z + c.w;
    __syncthreads();
    for (int off = 1; off < 256; off <<= 1) {
        int v = (t >= off) ? part[t - off] : 0;
        __syncthreads();
        part[t] += v;
        __syncthreads();
    }
    if (i0 < n) {
        int base = bsum[blockIdx.x] + ((t > 0) ? part[t - 1] : 0);
        int4 o;
        o.x = base;
        o.y = o.x + c.x;
        o.z = o.y + c.y;
        o.w = o.z + c.z;
        *reinterpret_cast<int4*>(&offsets[i0]) = o;
        *reinterpret_cast<int4*>(&cursor[i0]) = o;
    }
}

// ---------------- CSR fill: srow[pos] = row for each edge, bucketed by col ----------------

__global__ void fill_kernel(const int* __restrict__ rows, const int* __restrict__ cols,
                            int* __restrict__ cursor, int* __restrict__ srow, int E) {
    int e = blockIdx.x * blockDim.x + threadIdx.x;
    if (e < E) {
        int pos = atomicAdd(&cursor[cols[e]], 1);
        srow[pos] = rows[e];
    }
}

// ---------------- tiled f32 GEMM:  Y[N][COLS] = X[N][K] @ W[K][COLS] (+B) ----------------

template<int K, int COLS, int RPT, int CPT>
__launch_bounds__(256)
__global__ void gemm_kernel(const float* __restrict__ X,
                            const float* __restrict__ W,
                            const float* __restrict__ B,   // nullable
                            float* __restrict__ Y, int N) {
    constexpr int TILE_R = 64;
    constexpr int KC = 64;
    constexpr int NCHUNK = K / KC;
    constexpr int NCOLG = COLS / CPT;
    constexpr int NROWG = TILE_R / RPT;
    static_assert(NROWG * NCOLG == 256, "thread tiling must use 256 threads");

    __shared__ float wlds[K * COLS];
    __shared__ float xs[TILE_R][KC + 4];

    const int tid = threadIdx.x;
    const int r0 = blockIdx.x * TILE_R;

    constexpr int W4 = K * COLS / 4;
    const float4* Wg = reinterpret_cast<const float4*>(W);
    float4* wl4 = reinterpret_cast<float4*>(wlds);
    for (int i = tid; i < W4; i += 256) wl4[i] = Wg[i];

    const int tcol = tid % NCOLG;
    const int trow = tid / NCOLG;
    const int cbase = tcol * CPT;
    const int rbase = trow * RPT;

    float acc[RPT][CPT];
#pragma unroll
    for (int i = 0; i < RPT; ++i)
#pragma unroll
        for (int j = 0; j < CPT; ++j) acc[i][j] = 0.f;

    for (int ch = 0; ch < NCHUNK; ++ch) {
        __syncthreads();
#pragma unroll
        for (int j = 0; j < 4; ++j) {
            int flat4 = tid + 256 * j;       // 1024 float4 = 64 rows x 64 floats
            int rr = flat4 >> 4;
            int k4 = flat4 & 15;
            float4 v = make_float4(0.f, 0.f, 0.f, 0.f);
            int gr = r0 + rr;
            if (gr < N)
                v = *reinterpret_cast<const float4*>(&X[(size_t)gr * K + ch * KC + k4 * 4]);
            *reinterpret_cast<float4*>(&xs[rr][k4 * 4]) = v;
        }
        __syncthreads();
#pragma unroll
        for (int kk = 0; kk < KC; ++kk) {
            const int k = ch * KC + kk;
            float xv[RPT];
#pragma unroll
            for (int i = 0; i < RPT; ++i) xv[i] = xs[rbase + i][kk];
            float wv[CPT];
#pragma unroll
            for (int j = 0; j < CPT; ++j) wv[j] = wlds[k * COLS + cbase + j];
#pragma unroll
            for (int i = 0; i < RPT; ++i)
#pragma unroll
                for (int j = 0; j < CPT; ++j)
                    acc[i][j] = fmaf(xv[i], wv[j], acc[i][j]);
        }
    }

#pragma unroll
    for (int i = 0; i < RPT; ++i) {
        int r = r0 + rbase + i;
        if (r < N) {
#pragma unroll
            for (int j = 0; j < CPT; ++j) {
                float v = acc[i][j];
                if (B) v += B[cbase + j];
                Y[(size_t)r * COLS + cbase + j] = v;
            }
        }
    }
}

// ---------------- pull aggregation:  Y[node] = relu(Y[node] + sum_e norm * H[srow]) ----------------

template<int C>
__launch_bounds__(256)
__global__ void pull_kernel(const int* __restrict__ offsets,
                            const int* __restrict__ srow,
                            const float* __restrict__ dinv,
                            const float* __restrict__ H,
                            float* __restrict__ Y, int N) {
    constexpr int TPE = C / 4;
    int gid = blockIdx.x * blockDim.x + threadIdx.x;
    int node = gid / TPE;
    int lane = gid - node * TPE;
    if (node >= N) return;

    int e0 = offsets[node];
    int e1 = offsets[node + 1];
    float dc = dinv[node];

    const float4* H4 = reinterpret_cast<const float4*>(H);
    float4 acc = make_float4(0.f, 0.f, 0.f, 0.f);
    for (int j = e0; j < e1; ++j) {
        int r = srow[j];
        float nv = dc * dinv[r];
        float4 hv = H4[(size_t)r * TPE + lane];
        acc.x = fmaf(nv, hv.x, acc.x);
        acc.y = fmaf(nv, hv.y, acc.y);
        acc.z = fmaf(nv, hv.z, acc.z);
        acc.w = fmaf(nv, hv.w, acc.w);
    }

    float4* Y4 = reinterpret_cast<float4*>(Y);
    size_t yi = (size_t)node * TPE + lane;
    float4 y = Y4[yi];
    y.x = fmaxf(y.x + acc.x, 0.f);
    y.y = fmaxf(y.y + acc.y, 0.f);
    y.z = fmaxf(y.z + acc.z, 0.f);
    y.w = fmaxf(y.w + acc.w, 0.f);
    Y4[yi] = y;
}

// ---------------- launcher ----------------

extern "C" void kernel_launch(void* const* d_in, const int* in_sizes, int n_in,
                              void* d_out, int out_size, void* d_ws, size_t ws_size,
                              hipStream_t stream) {
    const float* x       = (const float*)d_in[0];
    const int*   eidx    = (const int*)d_in[1];
    const float* w1_init = (const float*)d_in[2];
    const float* w1_root = (const float*)d_in[3];
    const float* b1      = (const float*)d_in[4];
    const float* w2_init = (const float*)d_in[5];
    const float* w2_root = (const float*)d_in[6];
    const float* b2      = (const float*)d_in[7];
    float* out = (float*)d_out;

    const int* rows = eidx;                // edge_index[0] (source)
    const int* cols = eidx + N_EDGES;      // edge_index[1] (target)

    // workspace layout (4-byte units, all 16B-aligned)
    char* wsb = (char*)d_ws;
    float* dinv    = (float*)(wsb);                        //   100,000 f
    int*   counts  = (int*)  (wsb + 100000u * 4);          //   100,000 i
    int*   offsets = (int*)  (wsb + 200000u * 4);          //   100,001 i (pad to 100,004)
    int*   cursor  = (int*)  (wsb + 300004u * 4);          //   100,000 i
    int*   srow    = (int*)  (wsb + 400004u * 4);          // 1,000,000 i
    int*   bsum    = (int*)  (wsb + 1400004u * 4);         //       128 i
    float* h0      = (float*)(wsb + 1400132u * 4);         // 6,400,000 f  (reused as h2)
    float* agg1    = (float*)(wsb + 7800132u * 4);         // 6,400,000 f
    float* h2      = h0;
    // total: 14,200,132 * 4 B = 56.8 MB

    const int B = 256;
    const int NB_SCAN = cdiv(N_NODES, 1024);   // 98

    // ---- graph prep: degree, dinv, CSR by target ----
    hipMemsetAsync(counts, 0, N_NODES * sizeof(int), stream);
    hist_kernel<<<cdiv(N_EDGES, B), B, 0, stream>>>(cols, counts, N_EDGES);
    dinv_kernel<<<cdiv(N_NODES, B), B, 0, stream>>>(counts, dinv, N_NODES);
    block_sum_kernel<<<NB_SCAN, 256, 0, stream>>>(counts, bsum, N_NODES);
    scan_bsum_kernel<<<1, 128, 0, stream>>>(bsum, offsets, NB_SCAN, N_NODES);
    final_offsets_kernel<<<NB_SCAN, 256, 0, stream>>>(counts, bsum, offsets, cursor, N_NODES);
    fill_kernel<<<cdiv(N_EDGES, B), B, 0, stream>>>(rows, cols, cursor, srow, N_EDGES);

    // ---- layer 1 ----
    gemm_kernel<IN_CH, HID_CH, 4, 4><<<cdiv(N_NODES, 64), B, 0, stream>>>(x, w1_init, nullptr, h0, N_NODES);
    gemm_kernel<IN_CH, HID_CH, 4, 4><<<cdiv(N_NODES, 64), B, 0, stream>>>(x, w1_root, b1, agg1, N_NODES);
    // agg1 = relu(agg1 + pull(h0))   [double relu in ref == single relu]
    pull_kernel<HID_CH><<<cdiv(N_NODES * (HID_CH / 4), B), B, 0, stream>>>(offsets, srow, dinv, h0, agg1, N_NODES);

    // ---- layer 2 ----
    gemm_kernel<HID_CH, N_CLS, 2, 5><<<cdiv(N_NODES, 64), B, 0, stream>>>(agg1, w2_init, nullptr, h2, N_NODES);
    gemm_kernel<HID_CH, N_CLS, 2, 5><<<cdiv(N_NODES, 64), B, 0, stream>>>(agg1, w2_root, b2, out, N_NODES);
    // out = relu(out + pull(h2))
    pull_kernel<N_CLS><<<cdiv(N_NODES * (N_CLS / 4), B), B, 0, stream>>>(offsets, srow, dinv, h2, out, N_NODES);
}